// Round 12
// baseline (25.437 us; speedup 1.0000x reference)
//
#include <hip/hip_runtime.h>

// SpectralLoss: mean over all 8x8 blocks of (T (x-y) T^T)^2 * W
// Wave-cooperative DENSE loads: each wave owns one 64-block strip (a full
// block-row of an image plane = 8 x 2KB contiguous rows). Per row, two
// dense 1KB dwordx4 loads per array (lane stride 16B), diff in chunk space,
// then ds_bpermute the diff to block-owner lanes (16 bperm + 8 sel / row).
// Tests the theory that R9's 32B-stride sparse loads throttle VMEM to
// ~5 TB/s. Compute body + two-kernel reduction = R9 verbatim.

#define WG 256
#define NWG 768
#define INV_N (1.0f/12582912.0f)   // 16*3*512*512

typedef float v4f __attribute__((ext_vector_type(4)));

__global__ __launch_bounds__(WG, 3) void spectral_partial(
    const float* __restrict__ x,
    const float* __restrict__ y,
    const float* __restrict__ Tm,
    const float* __restrict__ Wm,
    float* __restrict__ ws)
{
    const int tid  = threadIdx.x;
    const int lane = tid & 63;
    const int gw   = blockIdx.x * 4 + (tid >> 6);  // strip id = global wave id
    const int img  = gw >> 6;                      // 64 strips per image plane
    const int hb   = gw & 63;                      // block-row within plane
    const int strip = img * 262144 + hb * 4096;    // float index of strip base
    const float* xs = x + strip + lane * 4;        // lane's dense 16B slot
    const float* ys = y + strip + lane * 4;

    // 8x8 DCT matrix; uniform addresses -> scalar (s_load) registers.
    float tT[8][8];
#pragma unroll
    for (int i = 0; i < 8; ++i) {
        float4 t0 = reinterpret_cast<const float4*>(Tm)[2*i];
        float4 t1 = reinterpret_cast<const float4*>(Tm)[2*i+1];
        tT[i][0]=t0.x; tT[i][1]=t0.y; tT[i][2]=t0.z; tT[i][3]=t0.w;
        tT[i][4]=t1.x; tT[i][5]=t1.y; tT[i][6]=t1.z; tT[i][7]=t1.w;
    }

    // bpermute addresses: this lane's block-row = chunks 2l, 2l+1 of the row.
    const int addr0 = ((2*lane)   & 63) * 4;
    const int addr1 = ((2*lane+1) & 63) * 4;
    const bool lo   = lane < 32;   // chunks 2l,2l+1 live in A-half vs B-half

    // Phase 1: per row -- dense loads, diff, redistribute, row-DCT into M.
    float M[8][8];
#pragma unroll
    for (int r = 0; r < 8; ++r) {
        v4f xa = *reinterpret_cast<const v4f*>(xs + r*512);         // chunks 0..63
        v4f xb = *reinterpret_cast<const v4f*>(xs + r*512 + 256);   // chunks 64..127
        v4f ya = *reinterpret_cast<const v4f*>(ys + r*512);
        v4f yb2= *reinterpret_cast<const v4f*>(ys + r*512 + 256);
        v4f dA = xa - ya;
        v4f dB = xb - yb2;

        float row[8];
#pragma unroll
        for (int c = 0; c < 4; ++c) {
            int a0 = __builtin_amdgcn_ds_bpermute(addr0, __float_as_int(dA[c]));
            int b0 = __builtin_amdgcn_ds_bpermute(addr0, __float_as_int(dB[c]));
            row[c]   = __int_as_float(lo ? a0 : b0);
            int a1 = __builtin_amdgcn_ds_bpermute(addr1, __float_as_int(dA[c]));
            int b1 = __builtin_amdgcn_ds_bpermute(addr1, __float_as_int(dB[c]));
            row[4+c] = __int_as_float(lo ? a1 : b1);
        }
#pragma unroll
        for (int l = 0; l < 8; ++l) {
            float acc = row[0]*tT[l][0];
#pragma unroll
            for (int j = 1; j < 8; ++j) acc += row[j]*tT[l][j];
            M[r][l] = acc;
        }
    }

    // Phase 2: s = sum_{i,l} W[i][l] * (sum_r T[i][r]*M[r][l])^2
    float s = 0.0f;
#pragma unroll
    for (int i = 0; i < 8; ++i) {
        float4 w0 = reinterpret_cast<const float4*>(Wm)[2*i];
        float4 w1 = reinterpret_cast<const float4*>(Wm)[2*i+1];
        float wr[8] = {w0.x,w0.y,w0.z,w0.w,w1.x,w1.y,w1.z,w1.w};
#pragma unroll
        for (int l = 0; l < 8; ++l) {
            float d = tT[i][0]*M[0][l];
#pragma unroll
            for (int r = 1; r < 8; ++r) d += tT[i][r]*M[r][l];
            s += wr[l]*d*d;
        }
    }

    // Deterministic workgroup reduction.
#pragma unroll
    for (int off = 32; off > 0; off >>= 1) s += __shfl_down(s, off, 64);
    __shared__ float wsum[WG/64];
    if ((tid & 63) == 0) wsum[tid >> 6] = s;
    __syncthreads();
    if (tid == 0) ws[blockIdx.x] = wsum[0] + wsum[1] + wsum[2] + wsum[3];
}

__global__ __launch_bounds__(256) void spectral_reduce(
    const float* __restrict__ ws, float* __restrict__ out)
{
    const int tid = threadIdx.x;
    float s = ws[tid] + ws[tid + 256] + ws[tid + 512];
#pragma unroll
    for (int off = 32; off > 0; off >>= 1) s += __shfl_down(s, off, 64);
    __shared__ float wsum[4];
    if ((tid & 63) == 0) wsum[tid >> 6] = s;
    __syncthreads();
    if (tid == 0) out[0] = (wsum[0]+wsum[1]+wsum[2]+wsum[3]) * INV_N;
}

extern "C" void kernel_launch(void* const* d_in, const int* in_sizes, int n_in,
                              void* d_out, int out_size, void* d_ws, size_t ws_size,
                              hipStream_t stream) {
    const float* x  = (const float*)d_in[0];   // input  (16,3,512,512) f32
    const float* y  = (const float*)d_in[1];   // target (16,3,512,512) f32
    const float* Tm = (const float*)d_in[2];   // 8x8 DCT
    const float* Wm = (const float*)d_in[3];   // 8x8 weight
    float* ws  = (float*)d_ws;                 // 768 partials
    float* out = (float*)d_out;                // scalar f32

    spectral_partial<<<NWG, WG, 0, stream>>>(x, y, Tm, Wm, ws);
    spectral_reduce<<<1, 256, 0, stream>>>(ws, out);
}

// Round 13
// 25.171 us; speedup vs baseline: 1.0106x; 1.0106x over previous
//
#include <hip/hip_runtime.h>

// SpectralLoss: mean over all 8x8 blocks of (T (x-y) T^T)^2 * W
// DENSE loads + DPP-pair redistribution. Each wave owns one strip (block-row
// of a plane, 8 x 2KB). Per row: 4 dense dwordx4 loads (16B lane stride --
// each 64B line touched once), diff, shfl_xor(1) to exchange half-block-rows
// between lane pairs (quad_perm DPP, ~free), then lane parity q computes
// output cols 4q..4q+3 of its two blocks (l>>1 and 32+(l>>1)).
// Two-kernel deterministic reduction (atomic tails cost +8us, R10).

#define WG 256
#define NWG 768
#define INV_N (1.0f/12582912.0f)   // 16*3*512*512

typedef float v4f __attribute__((ext_vector_type(4)));

__device__ __forceinline__ v4f shflx1(v4f v) {
    v4f r;
    r.x = __shfl_xor(v.x, 1, 64);
    r.y = __shfl_xor(v.y, 1, 64);
    r.z = __shfl_xor(v.z, 1, 64);
    r.w = __shfl_xor(v.w, 1, 64);
    return r;
}

__global__ __launch_bounds__(WG, 3) void spectral_partial(
    const float* __restrict__ x,
    const float* __restrict__ y,
    const float* __restrict__ Tm,
    const float* __restrict__ Wm,
    float* __restrict__ ws)
{
    const int tid  = threadIdx.x;
    const int lane = tid & 63;
    const int q    = lane & 1;                     // output-col half
    const int s    = blockIdx.x * 4 + (tid >> 6);  // strip id (3072 total)
    const int img  = s >> 6;
    const int hb   = s & 63;
    const int sbase = img * 262144 + hb * 4096;    // strip base (floats)

    // Full T uniform -> SGPRs (phase-2 rows i are uniform).
    float tT[8][8];
#pragma unroll
    for (int i = 0; i < 8; ++i) {
        float4 t0 = reinterpret_cast<const float4*>(Tm)[2*i];
        float4 t1 = reinterpret_cast<const float4*>(Tm)[2*i+1];
        tT[i][0]=t0.x; tT[i][1]=t0.y; tT[i][2]=t0.z; tT[i][3]=t0.w;
        tT[i][4]=t1.x; tT[i][5]=t1.y; tT[i][6]=t1.z; tT[i][7]=t1.w;
    }
    // Lane's 4 T-rows (output cols 4q..4q+3) -> VGPRs.
    float tl[4][8];
#pragma unroll
    for (int k = 0; k < 4; ++k) {
        const float* tr = Tm + (4*q + k)*8;
        float4 t0 = reinterpret_cast<const float4*>(tr)[0];
        float4 t1 = reinterpret_cast<const float4*>(tr)[1];
        tl[k][0]=t0.x; tl[k][1]=t0.y; tl[k][2]=t0.z; tl[k][3]=t0.w;
        tl[k][4]=t1.x; tl[k][5]=t1.y; tl[k][6]=t1.z; tl[k][7]=t1.w;
    }
    // Lane's W columns: wv[i] = W[i][4q..4q+3].
    v4f wv[8];
#pragma unroll
    for (int i = 0; i < 8; ++i)
        wv[i] = *reinterpret_cast<const v4f*>(Wm + i*8 + 4*q);

    // Phase 1: per strip-row, dense loads + pair exchange + row-DCT halves.
    // M_A = block (lane>>1), M_B = block 32+(lane>>1); cols 4q..4q+3.
    float MA[8][4], MB[8][4];
#pragma unroll
    for (int r = 0; r < 8; ++r) {
        const float* rb = x + sbase + r*512;
        const float* rc = y + sbase + r*512;
        v4f xA = *reinterpret_cast<const v4f*>(rb + 4*lane);
        v4f xB = *reinterpret_cast<const v4f*>(rb + 256 + 4*lane);
        v4f yA = *reinterpret_cast<const v4f*>(rc + 4*lane);
        v4f yB = *reinterpret_cast<const v4f*>(rc + 256 + 4*lane);
        v4f dA = xA - yA;
        v4f dB = xB - yB;
        v4f pA = shflx1(dA);          // partner's half of the same block-row
        v4f pB = shflx1(dB);

        float rowA[8], rowB[8];
#pragma unroll
        for (int j = 0; j < 4; ++j) {
            rowA[j]   = q ? pA[j] : dA[j];
            rowA[4+j] = q ? dA[j] : pA[j];
            rowB[j]   = q ? pB[j] : dB[j];
            rowB[4+j] = q ? dB[j] : pB[j];
        }
#pragma unroll
        for (int k = 0; k < 4; ++k) {
            float aA = rowA[0]*tl[k][0];
            float aB = rowB[0]*tl[k][0];
#pragma unroll
            for (int j = 1; j < 8; ++j) {
                aA += rowA[j]*tl[k][j];
                aB += rowB[j]*tl[k][j];
            }
            MA[r][k] = aA;
            MB[r][k] = aB;
        }
    }

    // Phase 2: d[i][4q+k] = sum_r T[i][r]*M[r][k]; s += w*d^2 (both blocks).
    float acc = 0.0f;
#pragma unroll
    for (int i = 0; i < 8; ++i) {
#pragma unroll
        for (int k = 0; k < 4; ++k) {
            float dA = tT[i][0]*MA[0][k];
            float dB = tT[i][0]*MB[0][k];
#pragma unroll
            for (int r = 1; r < 8; ++r) {
                dA += tT[i][r]*MA[r][k];
                dB += tT[i][r]*MB[r][k];
            }
            acc += wv[i][k]*(dA*dA + dB*dB);
        }
    }

    // Deterministic workgroup reduction.
#pragma unroll
    for (int off = 32; off > 0; off >>= 1) acc += __shfl_down(acc, off, 64);
    __shared__ float wsum[WG/64];
    if ((tid & 63) == 0) wsum[tid >> 6] = acc;
    __syncthreads();
    if (tid == 0) ws[blockIdx.x] = wsum[0] + wsum[1] + wsum[2] + wsum[3];
}

__global__ __launch_bounds__(256) void spectral_reduce(
    const float* __restrict__ ws, float* __restrict__ out)
{
    const int tid = threadIdx.x;
    float s = ws[tid] + ws[tid + 256] + ws[tid + 512];
#pragma unroll
    for (int off = 32; off > 0; off >>= 1) s += __shfl_down(s, off, 64);
    __shared__ float wsum[4];
    if ((tid & 63) == 0) wsum[tid >> 6] = s;
    __syncthreads();
    if (tid == 0) out[0] = (wsum[0]+wsum[1]+wsum[2]+wsum[3]) * INV_N;
}

extern "C" void kernel_launch(void* const* d_in, const int* in_sizes, int n_in,
                              void* d_out, int out_size, void* d_ws, size_t ws_size,
                              hipStream_t stream) {
    const float* x  = (const float*)d_in[0];   // input  (16,3,512,512) f32
    const float* y  = (const float*)d_in[1];   // target (16,3,512,512) f32
    const float* Tm = (const float*)d_in[2];   // 8x8 DCT
    const float* Wm = (const float*)d_in[3];   // 8x8 weight
    float* ws  = (float*)d_ws;                 // 768 partials
    float* out = (float*)d_out;                // scalar f32

    spectral_partial<<<NWG, WG, 0, stream>>>(x, y, Tm, Wm, ws);
    spectral_reduce<<<1, 256, 0, stream>>>(ws, out);
}

// Round 14
// 24.857 us; speedup vs baseline: 1.0233x; 1.0126x over previous
//
#include <hip/hip_runtime.h>

// SpectralLoss: mean over all 8x8 blocks of (T (x-y) T^T)^2 * W
// R9 structure, resubmitted verbatim (best measured: 23.7us).
// Evidence across R9-R13: the op sits on a latency x miss-queue roofline
// (~5 TB/s effective read at ~64 outstanding lines/CU, mixed L3/HBM
// latency) -- 100.7MB/5TB/s ~= 20us main + ~3.5us two-dispatch tail.
// Attacks on waves, in-flight loads, lane stride, and redistribution all
// landed within noise; single-kernel tails (+8us atomics) and cooperative
// launch (rejected) are closed. Two-kernel deterministic reduction.

#define WG 256
#define NWG 768
#define INV_N (1.0f/12582912.0f)   // 16*3*512*512

typedef float v4f __attribute__((ext_vector_type(4)));

__global__ __launch_bounds__(WG, 3) void spectral_partial(
    const float* __restrict__ x,
    const float* __restrict__ y,
    const float* __restrict__ Tm,
    const float* __restrict__ Wm,
    float* __restrict__ ws)
{
    const int tid = threadIdx.x;
    const int p   = blockIdx.x * WG + tid;   // 8x8-block id, one per thread
    const int img = p >> 12;                 // 4096 blocks per image plane
    const int rem = p & 4095;
    const int base = img * 262144 + (rem >> 6) * 4096 + (rem & 63) * 8;

    // Issue all 32 16B loads up front (compiler schedules ~10 in flight;
    // pinning more was neutral -- R11 -- queue depth, not issue, limits).
    v4f xa[16], yb[16];
#pragma unroll
    for (int r = 0; r < 8; ++r) {
        const v4f* xp = reinterpret_cast<const v4f*>(x + base + r*512);
        const v4f* yp = reinterpret_cast<const v4f*>(y + base + r*512);
        xa[2*r]   = xp[0];
        xa[2*r+1] = xp[1];
        yb[2*r]   = yp[0];
        yb[2*r+1] = yp[1];
    }

    // 8x8 DCT matrix; uniform addresses -> scalar (s_load) registers.
    float tT[8][8];
#pragma unroll
    for (int i = 0; i < 8; ++i) {
        float4 t0 = reinterpret_cast<const float4*>(Tm)[2*i];
        float4 t1 = reinterpret_cast<const float4*>(Tm)[2*i+1];
        tT[i][0]=t0.x; tT[i][1]=t0.y; tT[i][2]=t0.z; tT[i][3]=t0.w;
        tT[i][4]=t1.x; tT[i][5]=t1.y; tT[i][6]=t1.z; tT[i][7]=t1.w;
    }

    // Phase 1: M[r][l] = sum_j (x-y)[r][j] * T[l][j]; row regs die as M fills.
    float M[8][8];
#pragma unroll
    for (int r = 0; r < 8; ++r) {
        v4f a0 = xa[2*r], a1 = xa[2*r+1];
        v4f b0 = yb[2*r], b1 = yb[2*r+1];
        float row[8] = {a0.x-b0.x, a0.y-b0.y, a0.z-b0.z, a0.w-b0.w,
                        a1.x-b1.x, a1.y-b1.y, a1.z-b1.z, a1.w-b1.w};
#pragma unroll
        for (int l = 0; l < 8; ++l) {
            float acc = row[0]*tT[l][0];
#pragma unroll
            for (int j = 1; j < 8; ++j) acc += row[j]*tT[l][j];
            M[r][l] = acc;
        }
    }

    // Phase 2: s = sum_{i,l} W[i][l] * (sum_r T[i][r]*M[r][l])^2
    float s = 0.0f;
#pragma unroll
    for (int i = 0; i < 8; ++i) {
        float4 w0 = reinterpret_cast<const float4*>(Wm)[2*i];
        float4 w1 = reinterpret_cast<const float4*>(Wm)[2*i+1];
        float wr[8] = {w0.x,w0.y,w0.z,w0.w,w1.x,w1.y,w1.z,w1.w};
#pragma unroll
        for (int l = 0; l < 8; ++l) {
            float d = tT[i][0]*M[0][l];
#pragma unroll
            for (int r = 1; r < 8; ++r) d += tT[i][r]*M[r][l];
            s += wr[l]*d*d;
        }
    }

    // Deterministic workgroup reduction.
#pragma unroll
    for (int off = 32; off > 0; off >>= 1) s += __shfl_down(s, off, 64);
    __shared__ float wsum[WG/64];
    if ((tid & 63) == 0) wsum[tid >> 6] = s;
    __syncthreads();
    if (tid == 0) ws[blockIdx.x] = wsum[0] + wsum[1] + wsum[2] + wsum[3];
}

__global__ __launch_bounds__(256) void spectral_reduce(
    const float* __restrict__ ws, float* __restrict__ out)
{
    const int tid = threadIdx.x;
    float s = ws[tid] + ws[tid + 256] + ws[tid + 512];
#pragma unroll
    for (int off = 32; off > 0; off >>= 1) s += __shfl_down(s, off, 64);
    __shared__ float wsum[4];
    if ((tid & 63) == 0) wsum[tid >> 6] = s;
    __syncthreads();
    if (tid == 0) out[0] = (wsum[0]+wsum[1]+wsum[2]+wsum[3]) * INV_N;
}

extern "C" void kernel_launch(void* const* d_in, const int* in_sizes, int n_in,
                              void* d_out, int out_size, void* d_ws, size_t ws_size,
                              hipStream_t stream) {
    const float* x  = (const float*)d_in[0];   // input  (16,3,512,512) f32
    const float* y  = (const float*)d_in[1];   // target (16,3,512,512) f32
    const float* Tm = (const float*)d_in[2];   // 8x8 DCT
    const float* Wm = (const float*)d_in[3];   // 8x8 weight
    float* ws  = (float*)d_ws;                 // 768 partials
    float* out = (float*)d_out;                // scalar f32

    spectral_partial<<<NWG, WG, 0, stream>>>(x, y, Tm, Wm, ws);
    spectral_reduce<<<1, 256, 0, stream>>>(ws, out);
}